// Round 6
// baseline (328.811 us; speedup 1.0000x reference)
//
#include <hip/hip_runtime.h>

// Sobel conv (cross-correlation, zero-pad SAME) + sign-difference maps.
// x: [16,1,1024,1024] f32 -> y: [16,2,1024,1024], y0,y1: [16,1,1023,1023]
// Outputs concatenated flat in d_out (float32).
//
// f64 accumulation (weights {1,2} exact -> sign() matches high-precision ref;
// passed rounds 1-5, numerics unchanged).
//
// Round-6: NO in-loop barriers. __syncthreads() forces a vmcnt(0) drain, so
// round-5's per-row LDS transpose (2 barriers/row) serialized the row h+2
// prefetch into the critical path. Now: 4-row blocks stage all y0/y1 signs in
// 32KB LDS (aligned float4 ds_writes), ONE barrier, then a batched
// lane-contiguous store phase. XCD-bijective block swizzle for halo L2 reuse.

__device__ __forceinline__ void load_raw(const float* __restrict__ xb, int r, int t,
                                         float4& L, float4& C, float4& R) {
    if ((unsigned)r < 1024u) {                       // uniform branch (r is block-uniform)
        const float4* __restrict__ rp = (const float4*)(xb + (r << 10));
        L = rp[(t > 0) ? (t - 1) : 0];
        C = rp[t];
        R = rp[(t < 255) ? (t + 1) : 255];
    } else {
        L = C = R = make_float4(0.f, 0.f, 0.f, 0.f);  // zero-pad rows
    }
}

__device__ __forceinline__ void cvt_row(float4 L, float4 C, float4 R, int t,
                                        double* __restrict__ o /*[7]*/) {
    float lw = (t > 0)   ? L.w : 0.f;   // col w0-1 (zero-pad col -1)
    float r0 = (t < 255) ? R.x : 0.f;   // col w0+4 (zero-pad col 1024)
    float r1 = (t < 255) ? R.y : 0.f;   // col w0+5
    o[0] = (double)lw;  o[1] = (double)C.x; o[2] = (double)C.y; o[3] = (double)C.z;
    o[4] = (double)C.w; o[5] = (double)r0;  o[6] = (double)r1;
}

__device__ __forceinline__ float fsign(double v) {
    return (v > 0.0) ? 1.0f : ((v < 0.0) ? -1.0f : 0.0f);
}

__global__ __launch_bounds__(256) void sobel_sign_kernel(const float* __restrict__ x,
                                                         float* __restrict__ out) {
    const int t  = threadIdx.x;              // 0..255 -> cols 4t..4t+3
    // XCD-bijective swizzle: 4096 blocks, 8 XCDs, 512-block chunks per XCD.
    const int lb = (blockIdx.x & 7) * 512 + (blockIdx.x >> 3);
    const int b  = lb >> 8;                  // image
    const int hg = lb & 255;                 // 4-row group
    const int h0 = hg << 2;
    const int w0 = t << 2;

    const float* __restrict__ xb = x + ((size_t)b << 20);
    float* __restrict__ yb = out + ((size_t)b << 21);

    __shared__ float s0[4][1024];            // y0 signs, rows h0..h0+3
    __shared__ float s1[4][1024];            // y1 signs, rows h0..h0+3

    double r[3][7];                          // rolling f64 rows
    float4 L, C, R;                          // raw prefetch regs
    load_raw(xb, h0 - 1, t, L, C, R); cvt_row(L, C, R, t, r[0]);
    load_raw(xb, h0,     t, L, C, R); cvt_row(L, C, R, t, r[1]);
    load_raw(xb, h0 + 1, t, L, C, R);        // raw holds row h0+1

    float psgy[4];                           // sign(gy) of previous row

    #pragma unroll
    for (int it = 0; it < 4; ++it) {
        const int h = h0 + it;
        double* A0 = r[it % 3];              // row h-1
        double* A1 = r[(it + 1) % 3];        // row h
        double* A2 = r[(it + 2) % 3];        // row h+1
        cvt_row(L, C, R, t, A2);             // raw (row h+1) -> f64 window
        load_raw(xb, h + 2, t, L, C, R);     // prefetch row h+2 (it==3 -> h0+5)

        double tc[7], d[6];
        #pragma unroll
        for (int c = 0; c < 7; ++c) tc[c] = A0[c] + 2.0 * A1[c] + A2[c];
        #pragma unroll
        for (int c = 0; c < 6; ++c) d[c] = A0[c] - A2[c];

        double gx[5], gy[4];
        #pragma unroll
        for (int j = 0; j < 5; ++j) gx[j] = tc[j] - tc[j + 2];       // gx(h, w0+j)
        #pragma unroll
        for (int j = 0; j < 4; ++j) gy[j] = d[j] + 2.0 * d[j + 1] + d[j + 2];

        // y stores: [b, ch, h, w], float4-aligned, lane-contiguous
        size_t yo = ((size_t)h << 10) + (size_t)w0;
        *(float4*)(yb + yo) =
            make_float4((float)gx[0], (float)gx[1], (float)gx[2], (float)gx[3]);
        *(float4*)(yb + yo + (1u << 20)) =
            make_float4((float)gy[0], (float)gy[1], (float)gy[2], (float)gy[3]);

        float sgx[5], sgy[4];
        #pragma unroll
        for (int j = 0; j < 5; ++j) sgx[j] = fsign(gx[j]);
        #pragma unroll
        for (int j = 0; j < 4; ++j) sgy[j] = fsign(gy[j]);

        // Stage signs in LDS (aligned float4 ds_writes; no barrier needed:
        // each thread writes only its own slots).
        *(float4*)&s0[it][w0] = make_float4(sgx[0] - sgx[1], sgx[1] - sgx[2],
                                            sgx[2] - sgx[3], sgx[3] - sgx[4]);
        if (it > 0)                          // y1 row h-1 = psgy - sgy
            *(float4*)&s1[it - 1][w0] = make_float4(psgy[0] - sgy[0], psgy[1] - sgy[1],
                                                    psgy[2] - sgy[2], psgy[3] - sgy[3]);
        #pragma unroll
        for (int j = 0; j < 4; ++j) psgy[j] = sgy[j];
    }

    // Epilogue: y1 row h0+3 needs gy(h0+4) from rows h0+3 (r[4%3]=r[1]) and
    // h0+5 (raw regs; zeros if OOB).
    {
        double bn[7];
        cvt_row(L, C, R, t, bn);             // row h0+5
        double* B0 = r[1];                   // row h0+3
        float4 v;
        float* vp = &v.x;
        #pragma unroll
        for (int j = 0; j < 4; ++j) {
            double d0 = B0[j]     - bn[j];
            double d1 = B0[j + 1] - bn[j + 1];
            double d2 = B0[j + 2] - bn[j + 2];
            double gyn = d0 + 2.0 * d1 + d2;         // gy(h0+4, w0+j)
            vp[j] = psgy[j] - fsign(gyn);
        }
        *(float4*)&s1[3][w0] = v;
    }

    __syncthreads();                         // the ONLY barrier

    // Batched lane-contiguous store phase for y0/y1.
    const size_t NP = (size_t)1023 * 1023;   // 1046529
    float* __restrict__ Y0 = out + 33554432u + (size_t)b * NP;
    float* __restrict__ Y1 = out + 50298896u + (size_t)b * NP;
    #pragma unroll
    for (int rr = 0; rr < 4; ++rr) {
        const int hr = h0 + rr;
        if (hr < 1023) {                     // uniform; false only for hg==255,rr==3
            const size_t rb = (size_t)hr * 1023u;
            #pragma unroll
            for (int k = 0; k < 4; ++k) {
                const int c = t + (k << 8);
                if (c < 1023) {              // only lane t=255,k=3 masked
                    Y0[rb + c] = s0[rr][c];
                    Y1[rb + c] = s1[rr][c];
                }
            }
        }
    }
}

extern "C" void kernel_launch(void* const* d_in, const int* in_sizes, int n_in,
                              void* d_out, int out_size, void* d_ws, size_t ws_size,
                              hipStream_t stream) {
    const float* x = (const float*)d_in[0];
    float* out = (float*)d_out;
    dim3 grid(16 * 256), block(256);   // one block per (b, 4-row group)
    sobel_sign_kernel<<<grid, block, 0, stream>>>(x, out);
}